// Round 7
// baseline (217.064 us; speedup 1.0000x reference)
//
#include <hip/hip_runtime.h>
#include <math.h>

#define T_LEN 8192
#define NTRIALS 1024
#define TN ((size_t)T_LEN * NTRIALS)
#define KLEN 50
#define CHUNK 128
#define NCHUNK (T_LEN / CHUNK)   // 64 chunks/trial
#define FARW 256                 // unchecked f32 warmup
#define NEARW 256                // checked f64 warmup
#define WARM (FARW + NEARW)      // 512
#define PF 32                    // prefetch depth (rows)
#define BAND 1e-4f               // ambiguity band (f32 thr err <= ~3e-5)

// ---------------------------------------------------------------------------
// Kernel 1: basc[j] = bias + stim_conv_shifted[j] (f64) + f32 copy + params.
// ---------------------------------------------------------------------------
__global__ void prep_basc_kernel(const float* __restrict__ t,
                                 const float* __restrict__ stim,
                                 const float* __restrict__ bias,
                                 const float* __restrict__ k_stim,
                                 const float* __restrict__ hist_w,
                                 const float* __restrict__ hist_tau,
                                 double* __restrict__ dparams,
                                 double* __restrict__ basc,
                                 float* __restrict__ bascf) {
  int j = blockIdx.x * blockDim.x + threadIdx.x;
  if (j >= T_LEN) return;
  double dt = (double)t[1] - (double)t[0];
  if (j == 0) {
    dparams[0] = exp(-dt / (double)hist_tau[0]);  // decay0
    dparams[1] = exp(-dt / (double)hist_tau[1]);  // decay1
    dparams[2] = (double)hist_w[0];               // w0
    dparams[3] = (double)hist_w[1];               // w1
    dparams[4] = dt;
    dparams[5] = log(dt);
    basc[0] = (double)bias[0];
    bascf[0] = (float)(double)bias[0];
    return;
  }
  int n = j - 1;
  int mmax = n < (KLEN - 1) ? n : (KLEN - 1);
  double acc = 0.0;
  for (int m = 0; m <= mmax; ++m)
    acc += (double)k_stim[m] * (double)stim[n - m];
  double v = (double)bias[0] + dt * acc;
  basc[j] = v;
  bascf[j] = (float)v;
}

// Rare exact re-decision: f64 ground truth from the in-register r.
__device__ __noinline__ bool decide64r(float r, const double* __restrict__ basc,
                                       double dt, int j, double h) {
  double th = log(-log1p(-(double)r) / dt) - basc[j];
  return h > th;
}

// ---------------------------------------------------------------------------
// Kernel 2: fused speculative chunk-parallel scan. 1024 blocks x 1 wave
// (4 blocks/CU = 1 wave/SIMD). blockIdx = c*16 + tb: trial-group in LOW bits
// => per-XCD rnd column footprint 2 groups x 2 MB = 4 MB ~ L2, so warmup
// re-reads are L2 hits. Threshold computed inline from rnd (f32, off-chain);
// band-ambiguous steps re-decided exactly in f64 from the register r.
// Phases: FAR (<=256, f32 state, unchecked), NEAR (<=256, f64 state,
// checked), OUT (128, checked + stores).
// ---------------------------------------------------------------------------
__global__ __launch_bounds__(64, 1) void fused_scan_kernel(
    const float* __restrict__ rnd, const double* __restrict__ basc,
    const float* __restrict__ bascf, const double* __restrict__ dparams,
    float* __restrict__ out) {
  const int tid = threadIdx.x;
  const int tb  = blockIdx.x & 15;   // trial group (low bits -> XCD binding)
  const int c   = blockIdx.x >> 4;   // chunk
  const int i   = tb * 64 + tid;
  const double d0 = dparams[0], d1 = dparams[1];
  const double w0 = dparams[2], w1 = dparams[3];
  const double dt = dparams[4];
  const float d0f = (float)d0, d1f = (float)d1;
  const float w0f = (float)w0, w1f = (float)w1;
  const float ldtf = (float)dparams[5];

  const int jstart = c * CHUNK;
  const int nw    = jstart < WARM ? jstart : WARM;
  const int jw    = jstart - nw;
  const int nearn = nw < NEARW ? nw : NEARW;
  const int farn  = nw - nearn;
  const int j1    = jw + farn;

  const float* __restrict__ p = rnd + i;  // column i, row stride NTRIALS
  float bufA[PF], bufB[PF];
#pragma unroll
  for (int k = 0; k < PF; ++k) bufA[k] = p[(size_t)(jw + k) * NTRIALS];
  __builtin_amdgcn_sched_barrier(0);

  // ---------------- FAR: f32 state, unchecked decisions ----------------
  float a0 = 0.0f, a1 = 0.0f;
  for (int q = 0; q < farn; q += 2 * PF) {
    const int j0 = jw + q;
#pragma unroll
    for (int k = 0; k < PF; ++k) bufB[k] = p[(size_t)(j0 + PF + k) * NTRIALS];
    __builtin_amdgcn_sched_barrier(0);
#pragma unroll
    for (int k = 0; k < PF; ++k) {
      float th = logf(-log1pf(-bufA[k])) - ldtf - bascf[j0 + k];
      float h = a0 + a1;
      bool s = h > th;
      a0 = fmaf(d0f, a0, s ? w0f : 0.0f);
      a1 = fmaf(d1f, a1, s ? w1f : 0.0f);
    }
    __builtin_amdgcn_sched_barrier(0);
#pragma unroll
    for (int k = 0; k < PF; ++k) bufA[k] = p[(size_t)(j0 + 2 * PF + k) * NTRIALS];
    __builtin_amdgcn_sched_barrier(0);
#pragma unroll
    for (int k = 0; k < PF; ++k) {
      float th = logf(-log1pf(-bufB[k])) - ldtf - bascf[j0 + PF + k];
      float h = a0 + a1;
      bool s = h > th;
      a0 = fmaf(d0f, a0, s ? w0f : 0.0f);
      a1 = fmaf(d1f, a1, s ? w1f : 0.0f);
    }
    __builtin_amdgcn_sched_barrier(0);
  }

  // ---------------- NEAR: f64 state, band-checked exact ----------------
  double s0 = (double)a0, s1 = (double)a1;
  for (int q = 0; q < nearn; q += 2 * PF) {
    const int j0 = j1 + q;
#pragma unroll
    for (int k = 0; k < PF; ++k) bufB[k] = p[(size_t)(j0 + PF + k) * NTRIALS];
    __builtin_amdgcn_sched_barrier(0);
#pragma unroll
    for (int k = 0; k < PF; ++k) {
      float r = bufA[k];
      float th = logf(-log1pf(-r)) - ldtf - bascf[j0 + k];
      double h = s0 + s1;
      float d = (float)h - th;
      bool s = d > 0.0f;
      if (__builtin_expect(fabsf(d) < BAND, 0))
        s = decide64r(r, basc, dt, j0 + k, h);
      s0 = fma(d0, s0, s ? w0 : 0.0);
      s1 = fma(d1, s1, s ? w1 : 0.0);
    }
    __builtin_amdgcn_sched_barrier(0);
#pragma unroll
    for (int k = 0; k < PF; ++k) bufA[k] = p[(size_t)(j0 + 2 * PF + k) * NTRIALS];
    __builtin_amdgcn_sched_barrier(0);
#pragma unroll
    for (int k = 0; k < PF; ++k) {
      float r = bufB[k];
      float th = logf(-log1pf(-r)) - ldtf - bascf[j0 + PF + k];
      double h = s0 + s1;
      float d = (float)h - th;
      bool s = d > 0.0f;
      if (__builtin_expect(fabsf(d) < BAND, 0))
        s = decide64r(r, basc, dt, j0 + PF + k, h);
      s0 = fma(d0, s0, s ? w0 : 0.0);
      s1 = fma(d1, s1, s ? w1 : 0.0);
    }
    __builtin_amdgcn_sched_barrier(0);
  }

  // ---------------- OUT: 128 checked steps + stores ----------------
  float* __restrict__ po_ll = out + (size_t)jstart * NTRIALS + i;
  float* __restrict__ po_mk = po_ll + TN;
  for (int q = 0; q < CHUNK; q += 2 * PF) {
    const int j0 = jstart + q;
#pragma unroll
    for (int k = 0; k < PF; ++k) bufB[k] = p[(size_t)(j0 + PF + k) * NTRIALS];
    __builtin_amdgcn_sched_barrier(0);
#pragma unroll
    for (int k = 0; k < PF; ++k) {
      float r = bufA[k];
      float bf = bascf[j0 + k];
      float th = logf(-log1pf(-r)) - ldtf - bf;
      double h = s0 + s1;
      float d = (float)h - th;
      bool s = d > 0.0f;
      if (__builtin_expect(fabsf(d) < BAND, 0))
        s = decide64r(r, basc, dt, j0 + k, h);
      po_ll[(size_t)(q + k) * NTRIALS] = (float)h + bf;
      po_mk[(size_t)(q + k) * NTRIALS] = s ? 1.0f : 0.0f;
      s0 = fma(d0, s0, s ? w0 : 0.0);
      s1 = fma(d1, s1, s ? w1 : 0.0);
    }
    __builtin_amdgcn_sched_barrier(0);
    if (q + 2 * PF < CHUNK) {
#pragma unroll
      for (int k = 0; k < PF; ++k)
        bufA[k] = p[(size_t)(j0 + 2 * PF + k) * NTRIALS];
    }
    __builtin_amdgcn_sched_barrier(0);
#pragma unroll
    for (int k = 0; k < PF; ++k) {
      float r = bufB[k];
      float bf = bascf[j0 + PF + k];
      float th = logf(-log1pf(-r)) - ldtf - bf;
      double h = s0 + s1;
      float d = (float)h - th;
      bool s = d > 0.0f;
      if (__builtin_expect(fabsf(d) < BAND, 0))
        s = decide64r(r, basc, dt, j0 + PF + k, h);
      po_ll[(size_t)(q + PF + k) * NTRIALS] = (float)h + bf;
      po_mk[(size_t)(q + PF + k) * NTRIALS] = s ? 1.0f : 0.0f;
      s0 = fma(d0, s0, s ? w0 : 0.0);
      s1 = fma(d1, s1, s ? w1 : 0.0);
    }
    __builtin_amdgcn_sched_barrier(0);
  }
}

// Fallback (small ws): fully inline serial scan, correct but slow.
__global__ __launch_bounds__(64, 1) void glm_scan_inline_kernel(
    const float* __restrict__ rnd, const double* __restrict__ basc,
    const double* __restrict__ dparams, float* __restrict__ out) {
  const int i = blockIdx.x * 64 + threadIdx.x;
  const double d0 = dparams[0], d1 = dparams[1];
  const double w0 = dparams[2], w1 = dparams[3];
  const double dt = dparams[4];
  double s0 = 0.0, s1 = 0.0;
  float* __restrict__ out_ll = out;
  float* __restrict__ out_mk = out + TN;
  for (int j = 0; j < T_LEN; ++j) {
    double r = (double)rnd[(size_t)j * NTRIALS + i];
    double th = log(-log1p(-r) / dt) - basc[j];
    double hist = s0 + s1;
    bool spk = hist > th;
    out_ll[(size_t)j * NTRIALS + i] = (float)(basc[j] + hist);
    out_mk[(size_t)j * NTRIALS + i] = spk ? 1.0f : 0.0f;
    s0 = fma(d0, s0, spk ? w0 : 0.0);
    s1 = fma(d1, s1, spk ? w1 : 0.0);
  }
}

extern "C" void kernel_launch(void* const* d_in, const int* in_sizes, int n_in,
                              void* d_out, int out_size, void* d_ws, size_t ws_size,
                              hipStream_t stream) {
  const float* t        = (const float*)d_in[0];
  const float* stim     = (const float*)d_in[1];
  const float* rnd      = (const float*)d_in[2];
  const float* bias     = (const float*)d_in[3];
  const float* k_stim   = (const float*)d_in[4];
  const float* hist_w   = (const float*)d_in[5];
  const float* hist_tau = (const float*)d_in[6];
  float* out = (float*)d_out;

  char* ws = (char*)d_ws;
  const size_t off_bascf = 64;
  const size_t off_basc  = off_bascf + (size_t)T_LEN * 4;
  const size_t need      = off_basc + (size_t)T_LEN * 8;

  double* dparams = (double*)ws;
  float*  bascf   = (float*)(ws + off_bascf);
  double* basc    = (double*)(ws + off_basc);

  prep_basc_kernel<<<(T_LEN + 255) / 256, 256, 0, stream>>>(
      t, stim, bias, k_stim, hist_w, hist_tau, dparams, basc, bascf);

  if (ws_size >= need) {
    fused_scan_kernel<<<NCHUNK * 16, 64, 0, stream>>>(
        rnd, basc, bascf, dparams, out);
  }
  // (ws_size is always >= ~100 KB in this harness; no fallback needed, but
  //  keep the inline kernel referenced to avoid dead-strip surprises)
  else {
    glm_scan_inline_kernel<<<NTRIALS / 64, 64, 0, stream>>>(rnd, basc, dparams, out);
  }
}

// Round 8
// 92.453 us; speedup vs baseline: 2.3478x; 2.3478x over previous
//
#include <hip/hip_runtime.h>
#include <math.h>

#define T_LEN 8192
#define NTRIALS 1024
#define TN ((size_t)T_LEN * NTRIALS)
#define KLEN 50
#define CHUNK 256
#define NCHUNK (T_LEN / CHUNK)   // 32 chunks/trial
#define FARW 256                 // unchecked f32 warmup
#define NEARW 256                // checked f64 warmup
#define WARM (FARW + NEARW)      // 512
#define PF 32                    // prefetch depth (rows)  [R6 had 16]
#define BAND 1e-4f               // ambiguity band (thr32 err <= 3e-5, 3x margin)

// ---------------------------------------------------------------------------
// Kernel 1: basc[j] = bias + stim_conv_shifted[j] (f64) + f32 copy + params.
// ---------------------------------------------------------------------------
__global__ void prep_basc_kernel(const float* __restrict__ t,
                                 const float* __restrict__ stim,
                                 const float* __restrict__ bias,
                                 const float* __restrict__ k_stim,
                                 const float* __restrict__ hist_w,
                                 const float* __restrict__ hist_tau,
                                 double* __restrict__ dparams,
                                 double* __restrict__ basc,
                                 float* __restrict__ bascf) {
  int j = blockIdx.x * blockDim.x + threadIdx.x;
  if (j >= T_LEN) return;
  double dt = (double)t[1] - (double)t[0];
  if (j == 0) {
    dparams[0] = exp(-dt / (double)hist_tau[0]);  // decay0
    dparams[1] = exp(-dt / (double)hist_tau[1]);  // decay1
    dparams[2] = (double)hist_w[0];               // w0
    dparams[3] = (double)hist_w[1];               // w1
    dparams[4] = dt;
    basc[0] = (double)bias[0];
    bascf[0] = (float)(double)bias[0];
    return;
  }
  int n = j - 1;
  int mmax = n < (KLEN - 1) ? n : (KLEN - 1);
  double acc = 0.0;
  for (int m = 0; m <= mmax; ++m)
    acc += (double)k_stim[m] * (double)stim[n - m];
  double v = (double)bias[0] + dt * acc;
  basc[j] = v;
  bascf[j] = (float)v;
}

// ---------------------------------------------------------------------------
// Kernel 2: f32 thresholds via accurate libm (err <= ~3e-5 abs).
// spike <=> hist > thr; ties within BAND re-decided exactly in f64.
// ---------------------------------------------------------------------------
__global__ void prep_thr32_kernel(const float* __restrict__ rnd,
                                  const float* __restrict__ bascf,
                                  const double* __restrict__ dparams,
                                  float* __restrict__ thr32) {
  size_t m = ((size_t)blockIdx.x * blockDim.x + threadIdx.x) * 4;
  float dtf = (float)dparams[4];
  float4 r4 = *reinterpret_cast<const float4*>(rnd + m);
  float b = bascf[m >> 10];  // 4-pack never straddles a row
  float4 o;
  o.x = logf(-log1pf(-r4.x) / dtf) - b;
  o.y = logf(-log1pf(-r4.y) / dtf) - b;
  o.z = logf(-log1pf(-r4.z) / dtf) - b;
  o.w = logf(-log1pf(-r4.w) / dtf) - b;
  *reinterpret_cast<float4*>(thr32 + m) = o;
}

// Rare exact re-decision (band hit ~2e-5/lane-step): f64 ground truth.
__device__ __noinline__ bool decide64(const float* __restrict__ rnd,
                                      const double* __restrict__ basc,
                                      double dt, int j, int i, double h) {
  double r = (double)rnd[(size_t)j * NTRIALS + i];
  double t = log(-log1p(-r) / dt) - basc[j];
  return h > t;
}

// ---------------------------------------------------------------------------
// Kernel 3: speculative chunk-parallel scan. 512 blocks x 1 wave (2/CU).
// blockIdx = c*16 + tb: trial-group in LOW bits => all blocks re-reading a
// given thr column land on XCD tb%8 (per-XCD thr footprint ~4 MB ~ L2),
// so warmup re-reads are L2 hits, not HBM.
// Phases: FAR (<=256 steps, f32 state, unchecked), NEAR (<=256, f64 state,
// band-checked exact), OUT (256, NEAR + stores). PF=32 keeps 8 KB/wave in
// flight (R6's PF=16 measured in-flight-limited at 2.43 TB/s).
// ---------------------------------------------------------------------------
__global__ __launch_bounds__(64, 1) void spec_scan2_kernel(
    const float* __restrict__ thr, const float* __restrict__ rnd,
    const double* __restrict__ basc, const float* __restrict__ bascf,
    const double* __restrict__ dparams, float* __restrict__ out) {
  const int tid = threadIdx.x;
  const int tb  = blockIdx.x & 15;   // trial group (low bits -> XCD binding)
  const int c   = blockIdx.x >> 4;   // chunk
  const int i   = tb * 64 + tid;
  const double d0 = dparams[0], d1 = dparams[1];
  const double w0 = dparams[2], w1 = dparams[3];
  const double dt = dparams[4];
  const float d0f = (float)d0, d1f = (float)d1;
  const float w0f = (float)w0, w1f = (float)w1;

  const int jstart = c * CHUNK;
  const int nw    = jstart < WARM ? jstart : WARM;   // 0, 256, or 512
  const int jw    = jstart - nw;
  const int nearn = nw < NEARW ? nw : NEARW;
  const int farn  = nw - nearn;
  const int j1    = jw + farn;

  const float* __restrict__ p = thr + i;  // column i, row stride NTRIALS
  float bufA[PF], bufB[PF];
#pragma unroll
  for (int k = 0; k < PF; ++k) bufA[k] = p[(size_t)(jw + k) * NTRIALS];
  __builtin_amdgcn_sched_barrier(0);

  // ---------------- FAR: f32 state, unchecked decisions ----------------
  float a0 = 0.0f, a1 = 0.0f;
  for (int q = 0; q < farn; q += 2 * PF) {
    const int j0 = jw + q;
#pragma unroll
    for (int k = 0; k < PF; ++k) bufB[k] = p[(size_t)(j0 + PF + k) * NTRIALS];
    __builtin_amdgcn_sched_barrier(0);
#pragma unroll
    for (int k = 0; k < PF; ++k) {
      float h = a0 + a1;
      bool s = h > bufA[k];
      a0 = fmaf(d0f, a0, s ? w0f : 0.0f);
      a1 = fmaf(d1f, a1, s ? w1f : 0.0f);
    }
    __builtin_amdgcn_sched_barrier(0);
#pragma unroll
    for (int k = 0; k < PF; ++k) bufA[k] = p[(size_t)(j0 + 2 * PF + k) * NTRIALS];
    __builtin_amdgcn_sched_barrier(0);
#pragma unroll
    for (int k = 0; k < PF; ++k) {
      float h = a0 + a1;
      bool s = h > bufB[k];
      a0 = fmaf(d0f, a0, s ? w0f : 0.0f);
      a1 = fmaf(d1f, a1, s ? w1f : 0.0f);
    }
    __builtin_amdgcn_sched_barrier(0);
  }

  // ---------------- NEAR: f64 state, band-checked exact ----------------
  double s0 = (double)a0, s1 = (double)a1;
  for (int q = 0; q < nearn; q += 2 * PF) {
    const int j0 = j1 + q;
#pragma unroll
    for (int k = 0; k < PF; ++k) bufB[k] = p[(size_t)(j0 + PF + k) * NTRIALS];
    __builtin_amdgcn_sched_barrier(0);
#pragma unroll
    for (int k = 0; k < PF; ++k) {
      double h = s0 + s1;
      float d = (float)h - bufA[k];
      bool s = d > 0.0f;
      if (__builtin_expect(fabsf(d) < BAND, 0))
        s = decide64(rnd, basc, dt, j0 + k, i, h);
      s0 = fma(d0, s0, s ? w0 : 0.0);
      s1 = fma(d1, s1, s ? w1 : 0.0);
    }
    __builtin_amdgcn_sched_barrier(0);
#pragma unroll
    for (int k = 0; k < PF; ++k) bufA[k] = p[(size_t)(j0 + 2 * PF + k) * NTRIALS];
    __builtin_amdgcn_sched_barrier(0);
#pragma unroll
    for (int k = 0; k < PF; ++k) {
      double h = s0 + s1;
      float d = (float)h - bufB[k];
      bool s = d > 0.0f;
      if (__builtin_expect(fabsf(d) < BAND, 0))
        s = decide64(rnd, basc, dt, j0 + PF + k, i, h);
      s0 = fma(d0, s0, s ? w0 : 0.0);
      s1 = fma(d1, s1, s ? w1 : 0.0);
    }
    __builtin_amdgcn_sched_barrier(0);
  }

  // ---------------- OUT: 256 checked steps + stores ----------------
  float* __restrict__ po_ll = out + (size_t)jstart * NTRIALS + i;
  float* __restrict__ po_mk = po_ll + TN;
  for (int q = 0; q < CHUNK; q += 2 * PF) {
    const int j0 = jstart + q;
#pragma unroll
    for (int k = 0; k < PF; ++k) bufB[k] = p[(size_t)(j0 + PF + k) * NTRIALS];
    __builtin_amdgcn_sched_barrier(0);
#pragma unroll
    for (int k = 0; k < PF; ++k) {
      double h = s0 + s1;
      float d = (float)h - bufA[k];
      bool s = d > 0.0f;
      if (__builtin_expect(fabsf(d) < BAND, 0))
        s = decide64(rnd, basc, dt, j0 + k, i, h);
      po_ll[(size_t)(q + k) * NTRIALS] = (float)h + bascf[j0 + k];
      po_mk[(size_t)(q + k) * NTRIALS] = s ? 1.0f : 0.0f;
      s0 = fma(d0, s0, s ? w0 : 0.0);
      s1 = fma(d1, s1, s ? w1 : 0.0);
    }
    __builtin_amdgcn_sched_barrier(0);
    if (q + 2 * PF < CHUNK) {
#pragma unroll
      for (int k = 0; k < PF; ++k)
        bufA[k] = p[(size_t)(j0 + 2 * PF + k) * NTRIALS];
    }
    __builtin_amdgcn_sched_barrier(0);
#pragma unroll
    for (int k = 0; k < PF; ++k) {
      double h = s0 + s1;
      float d = (float)h - bufB[k];
      bool s = d > 0.0f;
      if (__builtin_expect(fabsf(d) < BAND, 0))
        s = decide64(rnd, basc, dt, j0 + PF + k, i, h);
      po_ll[(size_t)(q + PF + k) * NTRIALS] = (float)h + bascf[j0 + PF + k];
      po_mk[(size_t)(q + PF + k) * NTRIALS] = s ? 1.0f : 0.0f;
      s0 = fma(d0, s0, s ? w0 : 0.0);
      s1 = fma(d1, s1, s ? w1 : 0.0);
    }
    __builtin_amdgcn_sched_barrier(0);
  }
}

// Fallback (small ws): fully inline serial scan, correct but slow.
__global__ __launch_bounds__(64, 1) void glm_scan_inline_kernel(
    const float* __restrict__ rnd, const double* __restrict__ basc,
    const double* __restrict__ dparams, float* __restrict__ out) {
  const int i = blockIdx.x * 64 + threadIdx.x;
  const double d0 = dparams[0], d1 = dparams[1];
  const double w0 = dparams[2], w1 = dparams[3];
  const double dt = dparams[4];
  double s0 = 0.0, s1 = 0.0;
  float* __restrict__ out_ll = out;
  float* __restrict__ out_mk = out + TN;
  for (int j = 0; j < T_LEN; ++j) {
    double r = (double)rnd[(size_t)j * NTRIALS + i];
    double th = log(-log1p(-r) / dt) - basc[j];
    double hist = s0 + s1;
    bool spk = hist > th;
    out_ll[(size_t)j * NTRIALS + i] = (float)(basc[j] + hist);
    out_mk[(size_t)j * NTRIALS + i] = spk ? 1.0f : 0.0f;
    s0 = fma(d0, s0, spk ? w0 : 0.0);
    s1 = fma(d1, s1, spk ? w1 : 0.0);
  }
}

extern "C" void kernel_launch(void* const* d_in, const int* in_sizes, int n_in,
                              void* d_out, int out_size, void* d_ws, size_t ws_size,
                              hipStream_t stream) {
  const float* t        = (const float*)d_in[0];
  const float* stim     = (const float*)d_in[1];
  const float* rnd      = (const float*)d_in[2];
  const float* bias     = (const float*)d_in[3];
  const float* k_stim   = (const float*)d_in[4];
  const float* hist_w   = (const float*)d_in[5];
  const float* hist_tau = (const float*)d_in[6];
  float* out = (float*)d_out;

  char* ws = (char*)d_ws;
  const size_t off_bascf = 64;
  const size_t off_basc  = off_bascf + (size_t)T_LEN * 4;
  const size_t off_thr   = off_basc + (size_t)T_LEN * 8;
  const size_t need_full = off_thr + TN * 4;   // f32 thresholds
  const size_t need_min  = off_thr;

  double* dparams = (double*)ws;
  float*  bascf   = (float*)(ws + off_bascf);
  double* basc    = (double*)(ws + off_basc);
  float*  thr32   = (float*)(ws + off_thr);

  prep_basc_kernel<<<(T_LEN + 255) / 256, 256, 0, stream>>>(
      t, stim, bias, k_stim, hist_w, hist_tau, dparams, basc, bascf);

  if (ws_size >= need_full) {
    prep_thr32_kernel<<<(int)(TN / 4 / 256), 256, 0, stream>>>(
        rnd, bascf, dparams, thr32);
    spec_scan2_kernel<<<NCHUNK * 16, 64, 0, stream>>>(
        thr32, rnd, basc, bascf, dparams, out);
  } else if (ws_size >= need_min) {
    glm_scan_inline_kernel<<<NTRIALS / 64, 64, 0, stream>>>(rnd, basc, dparams, out);
  }
}